// Round 2
// baseline (9830.804 us; speedup 1.0000x reference)
//
#include <hip/hip_runtime.h>
#include <hip/hip_bf16.h>

// Seq2Seq: B=64 S=64 T=32 E=512 U=1024 VE=16000 VD=32000
// All float tensors are fp32 (per reference); ints int32; output fp32 (B, VD, T).
// Internally: GEMMs run bf16 MFMA (weights/activations converted on the fly).

typedef __hip_bfloat16 bf16;
typedef __bf16 bf16x8 __attribute__((ext_vector_type(8)));
typedef float f32x4 __attribute__((ext_vector_type(4)));

#define B_ 64
#define S_ 64
#define T_ 32
#define E_ 512
#define U_ 1024
#define VD_ 32000

__device__ __forceinline__ float sigf(float x) { return 1.0f / (1.0f + __expf(-x)); }

__device__ __forceinline__ bf16x8 frag_from_f32(const float* __restrict__ p) {
    float4 a = *(const float4*)p;
    float4 b = *(const float4*)(p + 4);
    bf16x8 r;
    r[0] = (__bf16)a.x; r[1] = (__bf16)a.y; r[2] = (__bf16)a.z; r[3] = (__bf16)a.w;
    r[4] = (__bf16)b.x; r[5] = (__bf16)b.y; r[6] = (__bf16)b.z; r[7] = (__bf16)b.w;
    return r;
}

// ---------------------------------------------------------------------------
// C = A(M x K, optional row-gather) @ W(N x K)^T [+bias]
// AF32/WF32: operand stored fp32 (converted to bf16 in the load path), else bf16.
// MODE 0: fp32 C row-major.  MODE 2: fp32 out[b][n][t], m = b*32+t (+bias).
// One wave: one 16-row M tile x NT 16-col N tiles. block=256 (4 waves).
// grid = (N/(64*NT), M/16).
// ---------------------------------------------------------------------------
template <int NT, int MODE, int AF32, int WF32>
__global__ __launch_bounds__(256) void gemm_bt(
    const void* __restrict__ A, int lda, const int* __restrict__ aidx,
    const void* __restrict__ W, int K, const float* __restrict__ bias,
    void* __restrict__ Cout, int N)
{
    const int wave = threadIdx.x >> 6;
    const int lane = threadIdx.x & 63;
    const int quad = lane >> 4;
    const int mn   = lane & 15;

    const int mt  = blockIdx.y;
    const int nt0 = (blockIdx.x * 4 + wave) * NT;

    const int m = mt * 16 + mn;
    const long arow = aidx ? (long)aidx[m] : (long)m;
    const long aoff = arow * (long)lda + quad * 8;
    const long woff = (long)(nt0 * 16 + mn) * K + quad * 8;

    f32x4 acc[NT];
#pragma unroll
    for (int i = 0; i < NT; i++) acc[i] = (f32x4){0.f, 0.f, 0.f, 0.f};

    for (int k0 = 0; k0 < K; k0 += 32) {
        bf16x8 af;
        if (AF32) af = frag_from_f32((const float*)A + aoff + k0);
        else      af = *(const bf16x8*)((const __bf16*)A + aoff + k0);
#pragma unroll
        for (int i = 0; i < NT; i++) {
            bf16x8 wf;
            if (WF32) wf = frag_from_f32((const float*)W + woff + (long)i * 16 * K + k0);
            else      wf = *(const bf16x8*)((const __bf16*)W + woff + (long)i * 16 * K + k0);
            acc[i] = __builtin_amdgcn_mfma_f32_16x16x32_bf16(af, wf, acc[i], 0, 0, 0);
        }
    }

    const int row0 = mt * 16 + quad * 4;
#pragma unroll
    for (int i = 0; i < NT; i++) {
        const int n = (nt0 + i) * 16 + mn;
        const float bv = bias ? bias[n] : 0.0f;
#pragma unroll
        for (int r = 0; r < 4; r++) {
            const int mrow = row0 + r;
            const float v = acc[i][r] + bv;
            if (MODE == 0) {
                ((float*)Cout)[(long)mrow * N + n] = v;
            } else {
                const int b = mrow >> 5, t = mrow & 31;  // T_ = 32
                ((float*)Cout)[((long)b * N + n) * T_ + t] = v;
            }
        }
    }
}

// fp32 -> bf16 bulk convert (n multiple of 4). grid-stride not needed; exact grid.
__global__ __launch_bounds__(256) void cvt_kernel(
    const float* __restrict__ src, bf16* __restrict__ dst, int n)
{
    const int i = (blockIdx.x * 256 + threadIdx.x) * 4;
    if (i < n) {
        float4 v = *(const float4*)(src + i);
        dst[i + 0] = __float2bfloat16(v.x);
        dst[i + 1] = __float2bfloat16(v.y);
        dst[i + 2] = __float2bfloat16(v.z);
        dst[i + 3] = __float2bfloat16(v.w);
    }
}

// ---------------------------------------------------------------------------
// LSTM gate pointwise: z = zx + zh + b_ih + b_hh; update c; emit h.
// grid = B_, block = 256, 4 u per thread. All math fp32; h emitted bf16.
// ---------------------------------------------------------------------------
__global__ __launch_bounds__(256) void gates_kernel(
    const float* __restrict__ zx, long zx_bs,
    const float* __restrict__ zh,
    const float* __restrict__ b_ih, const float* __restrict__ b_hh,
    float* __restrict__ c,
    bf16* __restrict__ obf, long obf_bs,       // encoder o row (bf16), nullable
    bf16* __restrict__ hbf,                    // h for next-step GEMM input
    bf16* __restrict__ hc, long hc_bs)         // hc_all second half, nullable
{
    const int b = blockIdx.x;
    const float* zxr = zx + (long)b * zx_bs;
    const float* zhr = zh + (long)b * (4 * U_);
#pragma unroll
    for (int i = 0; i < 4; i++) {
        const int u = threadIdx.x + i * 256;
        const float zi = zxr[u]          + zhr[u]          + b_ih[u]          + b_hh[u];
        const float zf = zxr[U_ + u]     + zhr[U_ + u]     + b_ih[U_ + u]     + b_hh[U_ + u];
        const float zg = zxr[2 * U_ + u] + zhr[2 * U_ + u] + b_ih[2 * U_ + u] + b_hh[2 * U_ + u];
        const float zo = zxr[3 * U_ + u] + zhr[3 * U_ + u] + b_ih[3 * U_ + u] + b_hh[3 * U_ + u];
        const long cu = (long)b * U_ + u;
        const float cv = sigf(zf) * c[cu] + sigf(zi) * tanhf(zg);
        const float hv = sigf(zo) * tanhf(cv);
        c[cu] = cv;
        const bf16 hb = __float2bfloat16(hv);
        if (obf) obf[(long)b * obf_bs + u] = hb;
        hbf[cu] = hb;
        if (hc) hc[(long)b * hc_bs + u] = hb;
    }
}

// ---------------------------------------------------------------------------
// Attention step: scores = q . o[b,s,:]; softmax over s; ctx -> hc first half.
// grid = B_, block = 256.
// ---------------------------------------------------------------------------
__global__ __launch_bounds__(256) void attn_kernel(
    const float* __restrict__ q, const bf16* __restrict__ o_enc,
    bf16* __restrict__ hc, long hc_bs)
{
    const int b = blockIdx.x;
    __shared__ float sw[S_];
    const int tid = threadIdx.x, wave = tid >> 6, lane = tid & 63;
    const float* qb = q + (long)b * U_;
    const bf16* ob = o_enc + (long)b * S_ * U_;

    for (int j = 0; j < 16; j++) {
        const int s = wave * 16 + j;
        const bf16* orow = ob + (long)s * U_;
        float acc = 0.f;
        for (int k = lane; k < U_; k += 64) acc += qb[k] * __bfloat162float(orow[k]);
        for (int off = 32; off; off >>= 1) acc += __shfl_down(acc, off);
        if (lane == 0) sw[s] = acc;
    }
    __syncthreads();
    if (wave == 0) {
        float v = sw[lane];
        float mx = v;
        for (int off = 32; off; off >>= 1) mx = fmaxf(mx, __shfl_xor(mx, off));
        const float e = __expf(v - mx);
        float sum = e;
        for (int off = 32; off; off >>= 1) sum += __shfl_xor(sum, off);
        sw[lane] = e / sum;
    }
    __syncthreads();
#pragma unroll
    for (int i = 0; i < 4; i++) {
        const int u = tid + i * 256;
        float acc = 0.f;
        for (int s = 0; s < S_; s++) acc += sw[s] * __bfloat162float(ob[(long)s * U_ + u]);
        hc[(long)b * hc_bs + u] = __float2bfloat16(acc);
    }
}

__global__ void build_idx(const int* __restrict__ y, int* __restrict__ idx)
{
    const int i = blockIdx.x * 256 + threadIdx.x;
    if (i < B_ * T_) {
        const int b = i >> 5, t = i & 31;
        idx[i] = y[b * (T_ + 1) + t];
    }
}

extern "C" void kernel_launch(void* const* d_in, const int* in_sizes, int n_in,
                              void* d_out, int out_size, void* d_ws, size_t ws_size,
                              hipStream_t stream)
{
    const int*   x       = (const int*)d_in[0];
    const int*   y       = (const int*)d_in[1];
    const float* enc_emb = (const float*)d_in[2];
    const float* dec_emb = (const float*)d_in[3];
    const float* W_ih_e  = (const float*)d_in[4];
    const float* W_hh_e  = (const float*)d_in[5];
    const float* b_ih_e  = (const float*)d_in[6];
    const float* b_hh_e  = (const float*)d_in[7];
    const float* Wa      = (const float*)d_in[8];
    const float* ba      = (const float*)d_in[9];
    const float* W_ih_d  = (const float*)d_in[10];
    const float* W_hh_d  = (const float*)d_in[11];
    const float* b_ih_d  = (const float*)d_in[12];
    const float* b_hh_d  = (const float*)d_in[13];
    const float* Wd      = (const float*)d_in[14];
    const float* bd      = (const float*)d_in[15];

    char* p = (char*)d_ws;
    auto alloc = [&](size_t bytes) { void* r = p; p += (bytes + 255) & ~255ull; return r; };
    float* zx_enc  = (float*)alloc((size_t)B_ * S_ * 4 * U_ * 4);   // 67 MB
    float* zx_dec  = (float*)alloc((size_t)B_ * T_ * 4 * U_ * 4);   // 34 MB
    bf16*  o_enc   = (bf16*)alloc((size_t)B_ * S_ * U_ * 2);        // 8.4 MB
    float* zh      = (float*)alloc((size_t)B_ * 4 * U_ * 4);        // 1 MB
    float* qbuf    = (float*)alloc((size_t)B_ * U_ * 4);
    float* cbuf    = (float*)alloc((size_t)B_ * U_ * 4);
    bf16*  hbf     = (bf16*)alloc((size_t)B_ * U_ * 2);
    bf16*  hc_all  = (bf16*)alloc((size_t)B_ * T_ * 2 * U_ * 2);    // 8.4 MB
    bf16*  Whh_e_b = (bf16*)alloc((size_t)4 * U_ * U_ * 2);         // 8.4 MB
    bf16*  Whh_d_b = (bf16*)alloc((size_t)4 * U_ * U_ * 2);         // 8.4 MB
    bf16*  Wa_b    = (bf16*)alloc((size_t)U_ * U_ * 2);             // 2.1 MB
    int*   dec_idx = (int*)alloc((size_t)B_ * T_ * 4);

    hipMemsetAsync(cbuf, 0, (size_t)B_ * U_ * 4, stream);
    hipMemsetAsync(hbf, 0, (size_t)B_ * U_ * 2, stream);
    build_idx<<<8, 256, 0, stream>>>(y, dec_idx);

    // Multi-use weights -> bf16 once per launch.
    cvt_kernel<<<(4 * U_ * U_) / 1024, 256, 0, stream>>>(W_hh_e, Whh_e_b, 4 * U_ * U_);
    cvt_kernel<<<(4 * U_ * U_) / 1024, 256, 0, stream>>>(W_hh_d, Whh_d_b, 4 * U_ * U_);
    cvt_kernel<<<(U_ * U_) / 1024, 256, 0, stream>>>(Wa, Wa_b, U_ * U_);

    // Input projections (biases folded into gates_kernel); fp32 A (gather) & W.
    gemm_bt<4, 0, 1, 1><<<dim3((4 * U_) / 256, (B_ * S_) / 16), 256, 0, stream>>>(
        enc_emb, E_, x, W_ih_e, E_, nullptr, zx_enc, 4 * U_);
    gemm_bt<4, 0, 1, 1><<<dim3((4 * U_) / 256, (B_ * T_) / 16), 256, 0, stream>>>(
        dec_emb, E_, dec_idx, W_ih_d, E_, nullptr, zx_dec, 4 * U_);

    // Encoder scan
    for (int t = 0; t < S_; t++) {
        gemm_bt<1, 0, 0, 0><<<dim3((4 * U_) / 64, B_ / 16), 256, 0, stream>>>(
            hbf, U_, nullptr, Whh_e_b, U_, nullptr, zh, 4 * U_);
        gates_kernel<<<B_, 256, 0, stream>>>(
            zx_enc + (long)t * 4 * U_, (long)S_ * 4 * U_, zh, b_ih_e, b_hh_e,
            cbuf, o_enc + (long)t * U_, (long)S_ * U_, hbf, nullptr, 0);
    }

    // Decoder scan
    for (int t = 0; t < T_; t++) {
        gemm_bt<1, 0, 0, 0><<<dim3(U_ / 64, B_ / 16), 256, 0, stream>>>(
            hbf, U_, nullptr, Wa_b, U_, ba, qbuf, U_);
        attn_kernel<<<B_, 256, 0, stream>>>(
            qbuf, o_enc, hc_all + (long)t * 2 * U_, (long)T_ * 2 * U_);
        gemm_bt<1, 0, 0, 0><<<dim3((4 * U_) / 64, B_ / 16), 256, 0, stream>>>(
            hbf, U_, nullptr, Whh_d_b, U_, nullptr, zh, 4 * U_);
        gates_kernel<<<B_, 256, 0, stream>>>(
            zx_dec + (long)t * 4 * U_, (long)T_ * 4 * U_, zh, b_ih_d, b_hh_d,
            cbuf, nullptr, 0, hbf, hc_all + (long)t * 2 * U_ + U_, (long)T_ * 2 * U_);
    }

    // logits: hc_all (2048 x 2048 bf16) @ Wd^T (32000 x 2048 fp32) + bd -> out[b][v][t]
    gemm_bt<4, 2, 0, 1><<<dim3(VD_ / 256, (B_ * T_) / 16), 256, 0, stream>>>(
        hc_all, 2 * U_, nullptr, Wd, 2 * U_, bd, d_out, VD_);
}